// Round 7
// baseline (310.527 us; speedup 1.0000x reference)
//
#include <hip/hip_runtime.h>

#define BB 4
#define CC 32
#define HH 512
#define WW 512
#define PLANE ((size_t)HH * WW)

typedef float fx2 __attribute__((ext_vector_type(2)));  // native vec for NT store

// ---------------------------------------------------------------------------
// Fused deformable-conv kernel, v3: pipelined gather.
// Round-6 post-mortem: 3x occupancy bought only 9% — per-wave latency
// exposure is the limiter, not wave supply. The gather phase was 8 strictly
// sequential {load-16 -> wait -> consume} groups = ~8 exposed L1/L2
// latencies per thread. v3 software-pipelines it like the conv: 2-channel
// groups (8 float2 loads), double-buffered A/B, group g+1's loads issued
// before group g is consumed — one exposed latency total.
//
// Conv: off_x/off_y = conv3x3(x, w_off[0:2]) + b_off[0:2].
//   Thread: 2 w-px (float2) x 1 row. Block: 256 threads = one 512-px row.
//   Grid: 2048 = 4 batches x 512 rows, XCD-band swizzled (each XCD owns a
//   256-row band -> conv reads and +-1px gathers hit XCD-local L2).
//   Edge px via lane shfl; lanes 0/63 do one masked 4B edge load per row.
//   2-deep channel software pipeline.
// Sample: two x-corners = one float2 gather; clamp folded into pair
//   weights A0/A1/B0/B1 vs xL (verified rounds 3/5/6). NT float2 stores.
// ---------------------------------------------------------------------------
__global__ __launch_bounds__(256, 6) void deform_fused_kernel(
    const float* __restrict__ x, const float* __restrict__ w_off,
    const float* __restrict__ b_off, float* __restrict__ out) {
  const int nb = gridDim.x;                       // 2048
  const int i  = blockIdx.x;
  const int j  = (i & 7) * (nb >> 3) + (i >> 3);  // XCD band swizzle
  const int b  = j >> 9;                          // 512 rows per batch
  const int h  = j & 511;                         // this block: row h

  const int t    = threadIdx.x;
  const int w2   = t << 1;                        // 0..510
  const int lane = t & 63;

  float2 a0v, a1v;                                // off_x / off_y for 2 px
  a0v.x = a0v.y = b_off[0];
  a1v.x = a1v.y = b_off[1];

  const float* xb = x + (size_t)b * CC * PLANE + (size_t)h * WW + w2;

  float2 mA[3], mB[3];                            // rows h-1..h+1, dbuf
  float  eA[3], eB[3];                            // boundary-lane extras

  auto load_ch = [&](int ci, float2* m, float* e) {
#pragma unroll
    for (int r = 0; r < 3; ++r) {
      const int hy = h - 1 + r;
      const float* q = xb + (size_t)ci * PLANE + (ptrdiff_t)(r - 1) * WW;
      if (hy >= 0 && hy < HH) {
        m[r] = *(const float2*)q;
        // lane 0 needs q[-1] (left wave edge), lane 63 needs q[2] (right).
        const float* ea = (lane == 0) ? q - 1 : q + 2;
        const bool eok = (lane == 0) ? (w2 > 0)
                                     : (lane == 63 && w2 < WW - 2);
        e[r] = eok ? *ea : 0.f;
      } else {
        m[r].x = m[r].y = 0.f;
        e[r] = 0.f;
      }
    }
  };

  auto compute_ch = [&](int ci, const float2* m, const float* e) {
    const float* wp0 = w_off + ci * 9;          // co=0: [ci][kh][kw]
    const float* wp1 = w_off + 288 + ci * 9;    // co=1
#pragma unroll
    for (int kh = 0; kh < 3; ++kh) {
      float vl = __shfl_up(m[kh].y, 1);         // px w2-1
      if (lane == 0) vl = e[kh];
      float vr = __shfl_down(m[kh].x, 1);       // px w2+2
      if (lane == 63) vr = e[kh];
      const float a0 = wp0[kh * 3 + 0], a1 = wp0[kh * 3 + 1], a2 = wp0[kh * 3 + 2];
      const float c0 = wp1[kh * 3 + 0], c1 = wp1[kh * 3 + 1], c2 = wp1[kh * 3 + 2];
      a0v.x += vl * a0 + m[kh].x * a1 + m[kh].y * a2;
      a0v.y += m[kh].x * a0 + m[kh].y * a1 + vr * a2;
      a1v.x += vl * c0 + m[kh].x * c1 + m[kh].y * c2;
      a1v.y += m[kh].x * c0 + m[kh].y * c1 + vr * c2;
    }
  };

  // 2-deep software pipeline over channels.
  load_ch(0, mA, eA);
  for (int ci = 0; ci < CC - 2; ci += 2) {
    load_ch(ci + 1, mB, eB);
    compute_ch(ci, mA, eA);
    load_ch(ci + 2, mA, eA);
    compute_ch(ci + 1, mB, eB);
  }
  load_ch(CC - 1, mB, eB);
  compute_ch(CC - 2, mA, eA);
  compute_ch(CC - 1, mB, eB);

  // ---- per-pixel sampling parameters (same arithmetic as verified split) --
  float A0[2], A1[2], B0[2], B1[2];
  int   r0[2], r1[2];
  const float offx[2] = {a0v.x, a0v.y};
  const float offy[2] = {a1v.x, a1v.y};
#pragma unroll
  for (int p = 0; p < 2; ++p) {
    const float ix = (float)(w2 + p) + offx[p];
    const float iy = (float)h + offy[p];
    const float x0f = floorf(ix);
    const float y0f = floorf(iy);
    const float wx1 = ix - x0f, wx0 = 1.f - wx1;
    const float wy1 = iy - y0f, wy0 = 1.f - wy1;
    const bool vx0 = (x0f >= 0.f) && (x0f <= (float)(WW - 1));
    const bool vx1 = (x0f + 1.f >= 0.f) && (x0f + 1.f <= (float)(WW - 1));
    const bool vy0 = (y0f >= 0.f) && (y0f <= (float)(HH - 1));
    const bool vy1 = (y0f + 1.f >= 0.f) && (y0f + 1.f <= (float)(HH - 1));
    const int xi0 = (int)fminf(fmaxf(x0f, 0.f), (float)(WW - 1));
    const int xi1 = (int)fminf(fmaxf(x0f + 1.f, 0.f), (float)(WW - 1));
    const int yi0 = (int)fminf(fmaxf(y0f, 0.f), (float)(HH - 1));
    const int yi1 = (int)fminf(fmaxf(y0f + 1.f, 0.f), (float)(HH - 1));
    const float w00 = wy0 * wx0 * ((vy0 && vx0) ? 1.f : 0.f);
    const float w01 = wy0 * wx1 * ((vy0 && vx1) ? 1.f : 0.f);
    const float w10 = wy1 * wx0 * ((vy1 && vx0) ? 1.f : 0.f);
    const float w11 = wy1 * wx1 * ((vy1 && vx1) ? 1.f : 0.f);
    const int xL = (int)fminf(fmaxf(x0f, 0.f), (float)(WW - 2));
    const int s0 = (xi0 > xL) ? 1 : 0;
    const int s1 = (xi1 > xL) ? 1 : 0;
    A0[p] = (s0 ? 0.f : w00) + (s1 ? 0.f : w01);
    A1[p] = (s0 ? w00 : 0.f) + (s1 ? w01 : 0.f);
    B0[p] = (s0 ? 0.f : w10) + (s1 ? 0.f : w11);
    B1[p] = (s0 ? w10 : 0.f) + (s1 ? w11 : 0.f);
    r0[p] = yi0 * WW + xL;
    r1[p] = yi1 * WW + xL;
  }

  // ---- gather + store: 16 groups of 2 channels, 2-deep software pipeline --
  const float* xp = x + (size_t)b * CC * PLANE;
  float* ob = out + (size_t)b * CC * PLANE + (size_t)h * WW + w2;

  auto load_grp = [&](int g, float2 (&t0)[2][2], float2 (&t1)[2][2]) {
    const float* pc = xp + (size_t)(g << 1) * PLANE;
#pragma unroll
    for (int c = 0; c < 2; ++c) {     // 8 float2 gathers back-to-back
#pragma unroll
      for (int p = 0; p < 2; ++p) {
        __builtin_memcpy(&t0[c][p], pc + r0[p], 8);
        __builtin_memcpy(&t1[c][p], pc + r1[p], 8);
      }
      pc += PLANE;
    }
  };
  auto consume_grp = [&](int g, const float2 (&t0)[2][2],
                         const float2 (&t1)[2][2]) {
    float* o = ob + (size_t)(g << 1) * PLANE;
#pragma unroll
    for (int c = 0; c < 2; ++c) {     // 8 FMA + coalesced float2 NT store
      fx2 v;
      v.x = t0[c][0].x * A0[0] + t0[c][0].y * A1[0] + t1[c][0].x * B0[0] + t1[c][0].y * B1[0];
      v.y = t0[c][1].x * A0[1] + t0[c][1].y * A1[1] + t1[c][1].x * B0[1] + t1[c][1].y * B1[1];
      __builtin_nontemporal_store(v, (fx2*)o);
      o += PLANE;
    }
  };

  float2 tA0[2][2], tA1[2][2], tB0[2][2], tB1[2][2];
  load_grp(0, tA0, tA1);
#pragma unroll 1
  for (int g = 0; g < 14; g += 2) {
    load_grp(g + 1, tB0, tB1);        // next group's loads in flight…
    consume_grp(g, tA0, tA1);         // …while consuming current
    load_grp(g + 2, tA0, tA1);
    consume_grp(g + 1, tB0, tB1);
  }
  load_grp(15, tB0, tB1);
  consume_grp(14, tA0, tA1);
  consume_grp(15, tB0, tB1);
}

extern "C" void kernel_launch(void* const* d_in, const int* in_sizes, int n_in,
                              void* d_out, int out_size, void* d_ws, size_t ws_size,
                              hipStream_t stream) {
  const float* x     = (const float*)d_in[0];
  const float* w_off = (const float*)d_in[1];
  const float* b_off = (const float*)d_in[2];
  float* out = (float*)d_out;

  deform_fused_kernel<<<2048, 256, 0, stream>>>(x, w_off, b_off, out);
}

// Round 8
// 299.478 us; speedup vs baseline: 1.0369x; 1.0369x over previous
//
#include <hip/hip_runtime.h>

#define BB 4
#define CC 32
#define HH 512
#define WW 512
#define PLANE ((size_t)HH * WW)

typedef float fx2 __attribute__((ext_vector_type(2)));  // native vec for NT store / pk-fma

// ---------------------------------------------------------------------------
// Fused deformable-conv kernel, v4.
// R7 post-mortem: pipelined gather regressed (SGPR 80, occ 48%, NT stores
// share vmcnt with gathers so the pipeline serialized on store completion)
// -> gather reverted to R6's verbatim form (measured 130 us).
// Conv change: R6 fetched halo px via 6 __shfl/channel = 192 ds_bpermute
// per thread sitting INSIDE the FMA dep chain (lgkmcnt stall every few
// FMAs; VALUBusy pinned at 28%). v4 instead loads an UNALIGNED float4 per
// row starting at w2-1: one load delivers vl,p0,p1,vr — zero cross-lane
// ops. Per-wave L1 cost unchanged (overlapping 16B loads span ~9 lines,
// same as the old float2). Image-edge lanes (t==0 / t==255 only) use a
// per-thread pointer shift (all loads in-bounds) + component remap via
// cndmask (pure VALU). Accumulators are packed fx2 (2 px) for v_pk_fma.
//
// Geometry: thread = 2 px x 1 row; block = 256 thr = one 512-px row;
// grid = 2048 (8 blocks/CU), XCD-band swizzle (each XCD owns a 256-row
// band -> conv reads and +-1px gathers hit XCD-local L2).
// Sample: two x-corners = one float2 gather; clamp folded into pair
// weights A0/A1/B0/B1 vs xL (verified rounds 3/5/6). NT float2 stores.
// ---------------------------------------------------------------------------
__global__ __launch_bounds__(256, 6) void deform_fused_kernel(
    const float* __restrict__ x, const float* __restrict__ w_off,
    const float* __restrict__ b_off, float* __restrict__ out) {
  const int nb = gridDim.x;                       // 2048
  const int i  = blockIdx.x;
  const int j  = (i & 7) * (nb >> 3) + (i >> 3);  // XCD band swizzle
  const int b  = j >> 9;                          // 512 rows per batch
  const int h  = j & 511;                         // this block: row h

  const int t  = threadIdx.x;
  const int w2 = t << 1;                          // 0..510

  const bool isL = (t == 0);                      // left image edge
  const bool isR = (t == 255);                    // right image edge
  const int  sh  = isL ? 0 : (isR ? -2 : -1);     // per-thread load shift

  fx2 acc0, acc1;                                 // off_x / off_y for 2 px
  acc0.x = acc0.y = b_off[0];
  acc1.x = acc1.y = b_off[1];

  // shifted base: all row loads are float4 at xs + ci*PLANE + (r-1)*WW
  const float* xs = x + (size_t)b * CC * PLANE + (size_t)h * WW + w2 + sh;

  float4 mA[3], mB[3];                            // rows h-1..h+1, dbuf

  auto load_ch = [&](int ci, float4* m) {
#pragma unroll
    for (int r = 0; r < 3; ++r) {
      const int hy = h - 1 + r;
      if (hy >= 0 && hy < HH) {
        m[r] = *(const float4*)(xs + (size_t)ci * PLANE + (ptrdiff_t)(r - 1) * WW);
      } else {
        m[r].x = m[r].y = m[r].z = m[r].w = 0.f;
      }
    }
  };

  auto compute_ch = [&](int ci, const float4* m) {
    const float* wp0 = w_off + ci * 9;          // co=0: [ci][kh][kw]
    const float* wp1 = w_off + 288 + ci * 9;    // co=1
#pragma unroll
    for (int kh = 0; kh < 3; ++kh) {
      const float4 v = m[kh];
      // component remap: generic (sh=-1): (vl,p0,p1,vr) = (x,y,z,w)
      //                  isL    (sh= 0): (0, x, y, z)
      //                  isR    (sh=-2): (y, z, w, 0)
      const float vl = isL ? 0.f : (isR ? v.y : v.x);
      const float p0 = isL ? v.x : (isR ? v.z : v.y);
      const float p1 = isL ? v.y : (isR ? v.w : v.z);
      const float vr = isL ? v.z : (isR ? 0.f : v.w);
      fx2 L, M, R;
      L.x = vl; L.y = p0;
      M.x = p0; M.y = p1;
      R.x = p1; R.y = vr;
      acc0 += L * wp0[kh * 3 + 0] + M * wp0[kh * 3 + 1] + R * wp0[kh * 3 + 2];
      acc1 += L * wp1[kh * 3 + 0] + M * wp1[kh * 3 + 1] + R * wp1[kh * 3 + 2];
    }
  };

  // 2-deep software pipeline over channels.
  load_ch(0, mA);
  for (int ci = 0; ci < CC - 2; ci += 2) {
    load_ch(ci + 1, mB);
    compute_ch(ci, mA);
    load_ch(ci + 2, mA);
    compute_ch(ci + 1, mB);
  }
  load_ch(CC - 1, mB);
  compute_ch(CC - 2, mA);
  compute_ch(CC - 1, mB);

  // ---- per-pixel sampling parameters (same arithmetic as verified split) --
  float A0[2], A1[2], B0[2], B1[2];
  int   r0[2], r1[2];
  const float offx[2] = {acc0.x, acc0.y};
  const float offy[2] = {acc1.x, acc1.y};
#pragma unroll
  for (int p = 0; p < 2; ++p) {
    const float ix = (float)(w2 + p) + offx[p];
    const float iy = (float)h + offy[p];
    const float x0f = floorf(ix);
    const float y0f = floorf(iy);
    const float wx1 = ix - x0f, wx0 = 1.f - wx1;
    const float wy1 = iy - y0f, wy0 = 1.f - wy1;
    const bool vx0 = (x0f >= 0.f) && (x0f <= (float)(WW - 1));
    const bool vx1 = (x0f + 1.f >= 0.f) && (x0f + 1.f <= (float)(WW - 1));
    const bool vy0 = (y0f >= 0.f) && (y0f <= (float)(HH - 1));
    const bool vy1 = (y0f + 1.f >= 0.f) && (y0f + 1.f <= (float)(HH - 1));
    const int xi0 = (int)fminf(fmaxf(x0f, 0.f), (float)(WW - 1));
    const int xi1 = (int)fminf(fmaxf(x0f + 1.f, 0.f), (float)(WW - 1));
    const int yi0 = (int)fminf(fmaxf(y0f, 0.f), (float)(HH - 1));
    const int yi1 = (int)fminf(fmaxf(y0f + 1.f, 0.f), (float)(HH - 1));
    const float w00 = wy0 * wx0 * ((vy0 && vx0) ? 1.f : 0.f);
    const float w01 = wy0 * wx1 * ((vy0 && vx1) ? 1.f : 0.f);
    const float w10 = wy1 * wx0 * ((vy1 && vx0) ? 1.f : 0.f);
    const float w11 = wy1 * wx1 * ((vy1 && vx1) ? 1.f : 0.f);
    const int xL = (int)fminf(fmaxf(x0f, 0.f), (float)(WW - 2));
    const int s0 = (xi0 > xL) ? 1 : 0;
    const int s1 = (xi1 > xL) ? 1 : 0;
    A0[p] = (s0 ? 0.f : w00) + (s1 ? 0.f : w01);
    A1[p] = (s0 ? w00 : 0.f) + (s1 ? w01 : 0.f);
    B0[p] = (s0 ? 0.f : w10) + (s1 ? 0.f : w11);
    B1[p] = (s0 ? w10 : 0.f) + (s1 ? w11 : 0.f);
    r0[p] = yi0 * WW + xL;
    r1[p] = yi1 * WW + xL;
  }

  // ---- gather + store: 8 groups of 4 channels (R6 verbatim, 130us) -------
  const float* xp = x + (size_t)b * CC * PLANE;
  float* ob = out + (size_t)b * CC * PLANE + (size_t)h * WW + w2;

#pragma unroll 1
  for (int cg = 0; cg < 8; ++cg) {
    float2 t0[4][2], t1[4][2];
    const float* pc = xp;
#pragma unroll
    for (int c = 0; c < 4; ++c) {       // issue 16 float2 gathers back-to-back
#pragma unroll
      for (int p = 0; p < 2; ++p) {
        __builtin_memcpy(&t0[c][p], pc + r0[p], 8);
        __builtin_memcpy(&t1[c][p], pc + r1[p], 8);
      }
      pc += PLANE;
    }
    float* o = ob;
#pragma unroll
    for (int c = 0; c < 4; ++c) {       // consume + coalesced float2 NT store
      fx2 v;
      v.x = t0[c][0].x * A0[0] + t0[c][0].y * A1[0] + t1[c][0].x * B0[0] + t1[c][0].y * B1[0];
      v.y = t0[c][1].x * A0[1] + t0[c][1].y * A1[1] + t1[c][1].x * B0[1] + t1[c][1].y * B1[1];
      __builtin_nontemporal_store(v, (fx2*)o);
      o += PLANE;
    }
    xp += (size_t)4 * PLANE;
    ob += (size_t)4 * PLANE;
  }
}

extern "C" void kernel_launch(void* const* d_in, const int* in_sizes, int n_in,
                              void* d_out, int out_size, void* d_ws, size_t ws_size,
                              hipStream_t stream) {
  const float* x     = (const float*)d_in[0];
  const float* w_off = (const float*)d_in[1];
  const float* b_off = (const float*)d_in[2];
  float* out = (float*)d_out;

  deform_fused_kernel<<<2048, 256, 0, stream>>>(x, w_off, b_off, out);
}